// Round 1
// baseline (284.011 us; speedup 1.0000x reference)
//
#include <hip/hip_runtime.h>

#define DIM 1024
#define HEADS 16
#define HDIM 64
#define SEQ 2048
#define BATCH 2
#define MTOT (BATCH*SEQ)     // 4096
#define ATT_SCALE 0.125f     // 64^-0.5

typedef __attribute__((ext_vector_type(8))) short bf16x8;
typedef __attribute__((ext_vector_type(4))) float f32x4;
typedef __attribute__((ext_vector_type(4))) unsigned int u32x4;

__device__ __forceinline__ unsigned short f2bf(float f) {
  unsigned int u = __builtin_bit_cast(unsigned int, f);
  u += 0x7FFFu + ((u >> 16) & 1u);   // round-to-nearest-even
  return (unsigned short)(u >> 16);
}
__device__ __forceinline__ unsigned int pack2bf(float lo, float hi) {
  return (unsigned int)f2bf(lo) | ((unsigned int)f2bf(hi) << 16);
}

// ---------- transpose + fp32->bf16 cast: dst[c][r] = bf16(src[r][c]) ----------
__global__ __launch_bounds__(256)
void transpose_cast_kernel(const float* __restrict__ src, unsigned short* __restrict__ dst,
                           int R, int C) {
  __shared__ float tile[32][33];
  const int bx = blockIdx.x * 32;      // over C
  const int by = blockIdx.y * 32;      // over R
  const int tx = threadIdx.x, ty = threadIdx.y;   // (32, 8)
  #pragma unroll
  for (int i = 0; i < 32; i += 8)
    tile[ty + i][tx] = src[(size_t)(by + ty + i) * C + bx + tx];
  __syncthreads();
  #pragma unroll
  for (int i = 0; i < 32; i += 8)
    dst[(size_t)(bx + ty + i) * R + by + tx] = f2bf(tile[tx][ty + i]);
}

// ---------- per-head V transpose (bf16): V[bh][n][d] -> Vt[bh][d][n] ----------
__global__ __launch_bounds__(256)
void transpose_v_kernel(const unsigned short* __restrict__ V, unsigned short* __restrict__ Vt) {
  __shared__ unsigned short tile[32][33];
  const int bh = blockIdx.z;
  const int n0 = blockIdx.x * 32, d0 = blockIdx.y * 32;
  const unsigned short* Vh = V + (size_t)bh * SEQ * HDIM;
  unsigned short* Vth = Vt + (size_t)bh * HDIM * SEQ;
  const int tx = threadIdx.x, ty = threadIdx.y;
  #pragma unroll
  for (int i = 0; i < 32; i += 8)
    tile[ty + i][tx] = Vh[(size_t)(n0 + ty + i) * HDIM + d0 + tx];
  __syncthreads();
  #pragma unroll
  for (int i = 0; i < 32; i += 8)
    Vth[(size_t)(d0 + ty + i) * SEQ + n0 + tx] = tile[tx][ty + i];
}

// ---------- GEMM: C[M x Ncols] = A(fp32)[M x K] * Bt(bf16)[Ncols x K]^T ----------
// 128x128 tile, 4 waves (2x2), BK=32, mfma_f32_16x16x32_bf16.
// EP==0: scatter to Q/K/V per-head bf16 buffers. EP==1: +bias, fp32 out.
template<int EP>
__global__ __launch_bounds__(256)
void gemm_kernel(const float* __restrict__ A, const unsigned short* __restrict__ Bt, int K,
                 unsigned short* __restrict__ qbuf, unsigned short* __restrict__ kbuf,
                 unsigned short* __restrict__ vbuf,
                 float* __restrict__ outp, const float* __restrict__ bias) {
  __shared__ unsigned short As[128 * 40];   // padded stride 40 (80B, 16B-aligned)
  __shared__ unsigned short Bs[128 * 40];
  const int tid = threadIdx.x;
  const int lane = tid & 63, wid = tid >> 6;
  const int lq = lane & 15, lg = lane >> 4;
  const int wrow = wid >> 1, wcol = wid & 1;
  const int rowbase = blockIdx.y * 128;
  const int colbase = blockIdx.x * 128;

  f32x4 acc[4][4];
  #pragma unroll
  for (int i = 0; i < 4; ++i)
    #pragma unroll
    for (int j = 0; j < 4; ++j) acc[i][j] = f32x4{0.f, 0.f, 0.f, 0.f};

  for (int kt = 0; kt < K; kt += 32) {
    // stage A tile [128 rows x 32 k], fp32 -> bf16
    #pragma unroll
    for (int i = 0; i < 2; ++i) {
      int idx = tid + i * 256;
      int row = idx >> 2;
      int kc = (idx & 3) * 8;
      const float4* src = reinterpret_cast<const float4*>(A + (size_t)(rowbase + row) * K + kt + kc);
      float4 f0 = src[0];
      float4 f1 = src[1];
      bf16x8 v;
      v[0] = (short)f2bf(f0.x); v[1] = (short)f2bf(f0.y);
      v[2] = (short)f2bf(f0.z); v[3] = (short)f2bf(f0.w);
      v[4] = (short)f2bf(f1.x); v[5] = (short)f2bf(f1.y);
      v[6] = (short)f2bf(f1.z); v[7] = (short)f2bf(f1.w);
      *reinterpret_cast<bf16x8*>(&As[row * 40 + kc]) = v;
    }
    // stage B tile [128 cols x 32 k] from Bt[col][k] (already transposed)
    #pragma unroll
    for (int i = 0; i < 2; ++i) {
      int idx = tid + i * 256;
      int col = idx >> 2;
      int kc = (idx & 3) * 8;
      bf16x8 v = *reinterpret_cast<const bf16x8*>(Bt + (size_t)(colbase + col) * K + kt + kc);
      *reinterpret_cast<bf16x8*>(&Bs[col * 40 + kc]) = v;
    }
    __syncthreads();
    bf16x8 af[4], bfr[4];
    #pragma unroll
    for (int m4 = 0; m4 < 4; ++m4)
      af[m4] = *reinterpret_cast<const bf16x8*>(&As[(wrow * 64 + m4 * 16 + lq) * 40 + lg * 8]);
    #pragma unroll
    for (int n4 = 0; n4 < 4; ++n4)
      bfr[n4] = *reinterpret_cast<const bf16x8*>(&Bs[(wcol * 64 + n4 * 16 + lq) * 40 + lg * 8]);
    #pragma unroll
    for (int m4 = 0; m4 < 4; ++m4)
      #pragma unroll
      for (int n4 = 0; n4 < 4; ++n4)
        acc[m4][n4] = __builtin_amdgcn_mfma_f32_16x16x32_bf16(af[m4], bfr[n4], acc[m4][n4], 0, 0, 0);
    __syncthreads();
  }

  // epilogue: C row=(lg*4+r), col=lq within each 16x16 fragment
  #pragma unroll
  for (int m4 = 0; m4 < 4; ++m4) {
    #pragma unroll
    for (int n4 = 0; n4 < 4; ++n4) {
      #pragma unroll
      for (int r = 0; r < 4; ++r) {
        int row = rowbase + wrow * 64 + m4 * 16 + lg * 4 + r;
        int col = colbase + wcol * 64 + n4 * 16 + lq;
        float val = acc[m4][n4][r];
        if (EP == 0) {
          int b = row >> 11, n = row & 2047;
          int which = col >> 10;              // 0=Q 1=K 2=V (wave-uniform)
          int hc = col & 1023;
          int h = hc >> 6, d = hc & 63;
          size_t off = ((size_t)(b * HEADS + h) * SEQ + n) * HDIM + d;
          unsigned short bv = f2bf(val);
          if (which == 0) qbuf[off] = bv;
          else if (which == 1) kbuf[off] = bv;
          else vbuf[off] = bv;
        } else {
          outp[(size_t)row * DIM + col] = val + bias[col];
        }
      }
    }
  }
}

// ---------- flash attention ----------
// Grid: 512 blocks = 32 (b*h) x 16 q-blocks of 128 rows. Block = 4 waves; each wave
// owns 32 q-rows (2 stripes of 16). Swapped-operand QK^T: S^T = mfma(K, Q) so the
// softmax row (q) is lane-local (col of C). P redistributed to 32-K B-frag layout
// via ds_bpermute; PV: O^T = mfma(V^T, P^T) accumulated fp32.
__global__ __launch_bounds__(256)
void attn_kernel(const unsigned short* __restrict__ Q, const unsigned short* __restrict__ Kb,
                 const unsigned short* __restrict__ Vt, float* __restrict__ O) {
  const int bid = blockIdx.x;
  const int qblk = bid & 15, bh = bid >> 4;
  const int b = bh >> 4, h = bh & 15;
  const int tid = threadIdx.x;
  const int lane = tid & 63, wid = tid >> 6;
  const int lq = lane & 15, lg = lane >> 4;
  const int q0 = qblk * 128 + wid * 32;
  const unsigned short* Qh = Q + (size_t)bh * SEQ * HDIM;
  const unsigned short* Kh = Kb + (size_t)bh * SEQ * HDIM;
  const unsigned short* Vh = Vt + (size_t)bh * HDIM * SEQ;

  // Q B-frags: B[k=d][col=q]; lane: q=lq, d=lg*8+j (+32 for dh=1)
  bf16x8 qf[2][2];
  #pragma unroll
  for (int s = 0; s < 2; ++s)
    #pragma unroll
    for (int dh = 0; dh < 2; ++dh)
      qf[s][dh] = *reinterpret_cast<const bf16x8*>(Qh + (size_t)(q0 + s * 16 + lq) * HDIM + dh * 32 + lg * 8);

  f32x4 acc[2][4];   // O^T: [stripe][d-chunk]; row=d (lg*4+r), col=q (lq)
  #pragma unroll
  for (int s = 0; s < 2; ++s)
    #pragma unroll
    for (int dc = 0; dc < 4; ++dc) acc[s][dc] = f32x4{0.f, 0.f, 0.f, 0.f};
  float mrun[2] = {-__builtin_inff(), -__builtin_inff()};
  float lrun[2] = {0.f, 0.f};

  for (int kt = 0; kt < SEQ; kt += 32) {
    // K A-frags for two 16-key tiles: A[row=key][k=d]
    bf16x8 kf[2][2];
    #pragma unroll
    for (int t = 0; t < 2; ++t)
      #pragma unroll
      for (int dh = 0; dh < 2; ++dh)
        kf[t][dh] = *reinterpret_cast<const bf16x8*>(Kh + (size_t)(kt + t * 16 + lq) * HDIM + dh * 32 + lg * 8);

    bf16x8 pf[2];
    #pragma unroll
    for (int s = 0; s < 2; ++s) {
      f32x4 z = f32x4{0.f, 0.f, 0.f, 0.f};
      f32x4 st0 = __builtin_amdgcn_mfma_f32_16x16x32_bf16(kf[0][0], qf[s][0], z, 0, 0, 0);
      st0 = __builtin_amdgcn_mfma_f32_16x16x32_bf16(kf[0][1], qf[s][1], st0, 0, 0, 0);
      f32x4 st1 = __builtin_amdgcn_mfma_f32_16x16x32_bf16(kf[1][0], qf[s][0], z, 0, 0, 0);
      st1 = __builtin_amdgcn_mfma_f32_16x16x32_bf16(kf[1][1], qf[s][1], st1, 0, 0, 0);
      // S^T layout: key=(lg*4+r) within tile, q=lq
      float tmax = -__builtin_inff();
      #pragma unroll
      for (int r = 0; r < 4; ++r) {
        st0[r] *= ATT_SCALE; st1[r] *= ATT_SCALE;
        tmax = fmaxf(tmax, fmaxf(st0[r], st1[r]));
      }
      tmax = fmaxf(tmax, __shfl_xor(tmax, 16));
      tmax = fmaxf(tmax, __shfl_xor(tmax, 32));
      float newm = fmaxf(mrun[s], tmax);
      float corr = __expf(mrun[s] - newm);
      mrun[s] = newm;
      float p0[4], p1[4], psum = 0.f;
      #pragma unroll
      for (int r = 0; r < 4; ++r) {
        p0[r] = __expf(st0[r] - newm);
        p1[r] = __expf(st1[r] - newm);
        psum += p0[r] + p1[r];
      }
      psum += __shfl_xor(psum, 16);
      psum += __shfl_xor(psum, 32);
      lrun[s] = lrun[s] * corr + psum;
      #pragma unroll
      for (int dc = 0; dc < 4; ++dc)
        #pragma unroll
        for (int r = 0; r < 4; ++r) acc[s][dc][r] *= corr;

      // Redistribute P^T to PV B-frag layout: lane l needs keys 8*lg..8*lg+7 at q=lq.
      // elem j=4a+r2  <-  tile (lg>>1), src lane (2*(lg&1)+a)*16+lq, reg r2.
      unsigned int u0 = pack2bf(p0[0], p0[1]), u1 = pack2bf(p0[2], p0[3]);
      unsigned int u2 = pack2bf(p1[0], p1[1]), u3 = pack2bf(p1[2], p1[3]);
      int i0 = (((lg & 1) * 2) * 16 + lq) * 4;
      int i1 = i0 + 64;
      int t0w0 = __builtin_amdgcn_ds_bpermute(i0, (int)u0);
      int t0w1 = __builtin_amdgcn_ds_bpermute(i0, (int)u1);
      int t0w2 = __builtin_amdgcn_ds_bpermute(i1, (int)u0);
      int t0w3 = __builtin_amdgcn_ds_bpermute(i1, (int)u1);
      int t1w0 = __builtin_amdgcn_ds_bpermute(i0, (int)u2);
      int t1w1 = __builtin_amdgcn_ds_bpermute(i0, (int)u3);
      int t1w2 = __builtin_amdgcn_ds_bpermute(i1, (int)u2);
      int t1w3 = __builtin_amdgcn_ds_bpermute(i1, (int)u3);
      bool lo = (lg < 2);
      u32x4 w;
      w[0] = (unsigned int)(lo ? t0w0 : t1w0);
      w[1] = (unsigned int)(lo ? t0w1 : t1w1);
      w[2] = (unsigned int)(lo ? t0w2 : t1w2);
      w[3] = (unsigned int)(lo ? t0w3 : t1w3);
      pf[s] = __builtin_bit_cast(bf16x8, w);
    }

    // PV: A = V^T frag (row=d, k=key), B = P^T frag
    #pragma unroll
    for (int dc = 0; dc < 4; ++dc) {
      bf16x8 vf = *reinterpret_cast<const bf16x8*>(Vh + (size_t)(dc * 16 + lq) * SEQ + kt + lg * 8);
      acc[0][dc] = __builtin_amdgcn_mfma_f32_16x16x32_bf16(vf, pf[0], acc[0][dc], 0, 0, 0);
      acc[1][dc] = __builtin_amdgcn_mfma_f32_16x16x32_bf16(vf, pf[1], acc[1][dc], 0, 0, 0);
    }
  }

  #pragma unroll
  for (int s = 0; s < 2; ++s) {
    float inv = 1.f / lrun[s];
    int qg = q0 + s * 16 + lq;
    #pragma unroll
    for (int dc = 0; dc < 4; ++dc)
      #pragma unroll
      for (int r = 0; r < 4; ++r) {
        int col = h * HDIM + dc * 16 + lg * 4 + r;
        O[((size_t)(b * SEQ + qg)) * DIM + col] = acc[s][dc][r] * inv;
      }
  }
}

extern "C" void kernel_launch(void* const* d_in, const int* in_sizes, int n_in,
                              void* d_out, int out_size, void* d_ws, size_t ws_size,
                              hipStream_t stream) {
  const float* x     = (const float*)d_in[0];
  const float* Wqkv  = (const float*)d_in[1];
  const float* Wout  = (const float*)d_in[2];
  const float* bout  = (const float*)d_in[3];
  float* out = (float*)d_out;

  char* ws = (char*)d_ws;
  unsigned short* WqkvT = (unsigned short*)ws; ws += (size_t)3 * DIM * DIM * 2;   // [3072][1024]
  unsigned short* WoutT = (unsigned short*)ws; ws += (size_t)DIM * DIM * 2;       // [1024][1024]
  unsigned short* Qb    = (unsigned short*)ws; ws += (size_t)32 * SEQ * HDIM * 2;
  unsigned short* Kbuf  = (unsigned short*)ws; ws += (size_t)32 * SEQ * HDIM * 2;
  unsigned short* Vbuf  = (unsigned short*)ws; ws += (size_t)32 * SEQ * HDIM * 2;
  unsigned short* Vtb   = (unsigned short*)ws; ws += (size_t)32 * SEQ * HDIM * 2;
  float* Obuf           = (float*)ws;          ws += (size_t)MTOT * DIM * 4;

  dim3 b32x8(32, 8);
  transpose_cast_kernel<<<dim3((3 * DIM) / 32, DIM / 32), b32x8, 0, stream>>>(Wqkv, WqkvT, DIM, 3 * DIM);
  transpose_cast_kernel<<<dim3(DIM / 32, DIM / 32), b32x8, 0, stream>>>(Wout, WoutT, DIM, DIM);
  gemm_kernel<0><<<dim3((3 * DIM) / 128, MTOT / 128), 256, 0, stream>>>(
      x, WqkvT, DIM, Qb, Kbuf, Vbuf, nullptr, nullptr);
  transpose_v_kernel<<<dim3(SEQ / 32, HDIM / 32, 32), b32x8, 0, stream>>>(Vbuf, Vtb);
  attn_kernel<<<dim3(512), 256, 0, stream>>>(Qb, Kbuf, Vtb, Obuf);
  gemm_kernel<1><<<dim3(DIM / 128, MTOT / 128), 256, 0, stream>>>(
      Obuf, WoutT, DIM, nullptr, nullptr, nullptr, out, bout);
}